// Round 6
// baseline (312.028 us; speedup 1.0000x reference)
//
#include <hip/hip_runtime.h>

// Retention, B=4 S=4096 H=1024, gamma=0.96875.
// out[b,i,:] = sum_{j<=i} gamma^(i-j) * (q_i . k_j) * v_j
//
// Pipeline (128x128 MFMA GEMMs, BK=64, 32KB LDS, ~4-5 blocks/CU, XCD swizzle):
//   x~   = [x | 1 | 0pad63]               (16384 x 1088 bf16)
//   W~qT = [Wq^T ; bq ; 0pad]             (1152 x 1024)   W~kT same
//   P1   = W~kT . W~qT^T                  (1152 x 1088)   (hidden under cvt_x)
//   G    = x~ . P1^T                      (16384 x 1152 -> clip 1088)
//   Vt   = (Wv . x~^T) scattered          ([b][h][s] bf16)
//   Pb   = band(G . x~^T) * gamma^d       (128 qtiles x 128 x 640, 5 key-slots of 128)
//   out  = Pb . Vt^T (banded K<=640 via kStart)  (f32)
// Band window 512..639; truncated tail < 1e-5 << threshold.
//
// R6 change: the 256^2 1-block/CU deep-pipeline path (R2-R5) plateaued at
// MfmaUtil 29% — with a single resident block, every LDS/barrier/vmcnt bubble
// lands on the critical path, and the 320/448-block grids quantize terribly
// (g256_g: 2 rounds at 62% util).  Reverting to the m97-proven regime: 128^2
// tile, 256 thr, 32KB LDS, simple 2-barrier K-loop, 4-5 co-resident blocks/CU
// (co-residency absorbs the stalls, m114), small blocks pack evenly — while
// KEEPING R5's coalesced LDS-image epilogue (R1's 128^2 lost ~35% to 64
// scattered 2B stores/thread) and the launch fusion.  Also back to the
// 128-granular band (640 vs 768 K: -9 GF) and kStart clipping (no pb zeroing).

typedef __attribute__((ext_vector_type(8))) short short8;   // 8 bf16 = 4 VGPRs
typedef __attribute__((ext_vector_type(4))) float floatx4;  // MFMA 16x16 C/D

#define MFMA(a, b, c) __builtin_amdgcn_mfma_f32_16x16x32_bf16((a), (b), (c), 0, 0, 0)

#define B_SZ   4
#define S_LEN  4096
#define H_DIM  1024
#define NROWS  (B_SZ * S_LEN)          // 16384
#define HP     1088                    // padded H+1 (17*64)
#define WR     1152                    // padded weight rows (9*128)
#define LOG2G  (-0.045803690f)         // log2(0.96875)

__device__ __forceinline__ unsigned short f32_to_bf16_rn(float f) {
    unsigned int u = __float_as_uint(f);
    u += 0x7FFFu + ((u >> 16) & 1u);   // round-to-nearest-even
    return (unsigned short)(u >> 16);
}

#define GLOAD_LDS16(gptr, lptr)                                                        \
    __builtin_amdgcn_global_load_lds((__attribute__((address_space(1))) void*)(gptr),  \
                                     (__attribute__((address_space(3))) void*)(lptr),  \
                                     16, 0, 0)

// ---------------------------------------------------------------- elementwise bodies
__device__ __forceinline__ void cvt_bf16_body(int i, const float* __restrict__ src,
                                              unsigned short* __restrict__ dst, int n4) {
    if (i >= n4) return;
    float4 v = ((const float4*)src)[i];
    ushort4 o;
    o.x = f32_to_bf16_rn(v.x);
    o.y = f32_to_bf16_rn(v.y);
    o.z = f32_to_bf16_rn(v.z);
    o.w = f32_to_bf16_rn(v.w);
    ((ushort4*)dst)[i] = o;
}

// x -> x~ rows of HP (cols 0..1023)
__device__ __forceinline__ void cvt_x_body(int idx, const float* __restrict__ src,
                                           unsigned short* __restrict__ dst) {
    int row = idx >> 7, c8 = (idx & 127) * 8;
    const float4* s = (const float4*)(src + (size_t)row * H_DIM + c8);
    float4 a = s[0], b = s[1];
    ushort4 o0, o1;
    o0.x = f32_to_bf16_rn(a.x); o0.y = f32_to_bf16_rn(a.y);
    o0.z = f32_to_bf16_rn(a.z); o0.w = f32_to_bf16_rn(a.w);
    o1.x = f32_to_bf16_rn(b.x); o1.y = f32_to_bf16_rn(b.y);
    o1.z = f32_to_bf16_rn(b.z); o1.w = f32_to_bf16_rn(b.w);
    ushort4* d = (ushort4*)(dst + (size_t)row * HP + c8);
    d[0] = o0; d[1] = o1;
}

// cols 1024..1087 of x~: 1.0 at col 1024, zeros elsewhere  (idx over 16384*8)
__device__ __forceinline__ void fill_pad_body(int idx, unsigned short* __restrict__ dst) {
    int row = idx >> 3, c = idx & 7;
    uint4 v; v.x = (c == 0) ? 0x00003F80u : 0u; v.y = 0u; v.z = 0u; v.w = 0u;
    *(uint4*)(dst + (size_t)row * HP + 1024 + c * 8) = v;
}

// W (f32) + bias -> [W^T ; bias ; 0] bf16, 1152x1024.  (bx in [0,8), by in [0,36))
__device__ __forceinline__ void tr_cvt_body(float (&Lt)[128][33],
                                            const float* __restrict__ Wsrc,
                                            const float* __restrict__ bias,
                                            unsigned short* __restrict__ dst,
                                            int bx, int by, int tid) {
    if (by >= 32) {                                // rows 1024..1151: bias row + zeros
        if (bx != 0) return;
        const int h0 = by * 32;
#pragma unroll
        for (int i = 0; i < 128; ++i) {
            int idx = i * 256 + tid;               // 32*1024
            int r = idx >> 10, cc = idx & 1023;
            int h = h0 + r;
            float v = (h == 1024) ? bias[cc] : 0.0f;
            dst[(size_t)h * 1024 + cc] = f32_to_bf16_rn(v);
        }
        return;
    }
    const int w0 = bx * 128, h0 = by * 32;
#pragma unroll
    for (int i = 0; i < 16; ++i) {
        int idx = i * 256 + tid;
        int r = idx >> 5, cc = idx & 31;
        Lt[r][cc] = Wsrc[(size_t)(w0 + r) * 1024 + h0 + cc];
    }
    __syncthreads();
#pragma unroll
    for (int i = 0; i < 16; ++i) {
        int idx = i * 256 + tid;
        int hh = idx >> 7, ww = idx & 127;
        dst[(size_t)(h0 + hh) * 1024 + w0 + ww] = f32_to_bf16_rn(Lt[ww][hh]);
    }
}

// ---------------------------------------------------------------- 128x128 MFMA GEMM body
// C[n,o] = sum_k A[n,k]*W[o,k].  BK=64 as two 32-halves (32 KB LDS total), 2 barriers
// per 64-K step (m97 structure; multi-block co-residency hides the drains).
// Epilogue: acc -> bank-swizzled 128x128 LDS image (col ^= ((row>>2)&3)<<4) reusing
// the staging LDS, then 8 coalesced 16B stores/thread.
// MODE 0: bf16 row-major store (col-clip p0)   MODE 1: Vt scatter (bx=htile, by=stile)
// MODE 2: decay epilogue -> Pb band            MODE 3: banded-K (kStart), f32 store
template <int MODE>
__device__ __forceinline__ void gemm_body(unsigned short (&sh)[16384],
                                          int bx, int by,
                                          const unsigned short* __restrict__ A, int lda,
                                          const unsigned short* __restrict__ W, int ldw,
                                          void* __restrict__ outp, int ldo, int K, int p0) {
    const int tid  = threadIdx.x;
    const int lane = tid & 63;
    const int w4   = tid >> 6;
    const int wm   = w4 >> 1, wn = w4 & 1;
    const int l15  = lane & 15;
    const int q    = lane >> 4;
    const int q8   = q * 8;
    const int q4   = q * 4;

    int aRow0 = 0, wRow0 = 0, kStart = 0;
    const unsigned short* Ap = A;
    const unsigned short* Wp = W;
    const int tT = by;
    const int tl = tT & 31;
    int jt = 0;

    if (MODE == 0) {
        aRow0 = by * 128; wRow0 = bx * 128;
    } else if (MODE == 1) {
        aRow0 = bx * 128; wRow0 = by * 128;       // bx=h-tile, by=x-row-tile
    } else if (MODE == 2) {
        jt = tl - 4 + bx;
        if (jt < 0) return;                        // block-uniform early exit
        aRow0 = tT * 128;
        wRow0 = (tT >> 5) * S_LEN + jt * 128;
    } else {                                       // MODE 3
        kStart = (tl < 4) ? (4 - tl) * 128 : 0;
        Ap = A + (size_t)tT * 128 * 640;
        Wp = W + (size_t)((tT >> 5) * H_DIM + bx * 128) * S_LEN + (ptrdiff_t)(tl - 4) * 128;
    }

    unsigned short* As0 = &sh[0];                  // [2][128*32]
    unsigned short* Bs0 = &sh[8192];               // [2][128*32]

    floatx4 acc[4][4];
#pragma unroll
    for (int i = 0; i < 4; ++i)
#pragma unroll
        for (int j = 0; j < 4; ++j) acc[i][j] = (floatx4)0.0f;

    for (int k0 = kStart; k0 < K; k0 += 64) {
        __syncthreads();
#pragma unroll
        for (int p = 0; p < 2; ++p) {
            const int c = p * 256 + tid;           // chunk id in [0,512): row=c>>2, ch=c&3
            const unsigned short* gA = Ap + (size_t)(aRow0 + (c >> 2)) * lda + k0 + (c & 3) * 8;
            const unsigned short* gW = Wp + (size_t)(wRow0 + (c >> 2)) * ldw + k0 + (c & 3) * 8;
            char* dA0 = (char*)As0          + (size_t)(p * 256 + w4 * 64) * 16;
            char* dA1 = (char*)(As0 + 4096) + (size_t)(p * 256 + w4 * 64) * 16;
            char* dB0 = (char*)Bs0          + (size_t)(p * 256 + w4 * 64) * 16;
            char* dB1 = (char*)(Bs0 + 4096) + (size_t)(p * 256 + w4 * 64) * 16;
            GLOAD_LDS16(gA,      dA0);
            GLOAD_LDS16(gA + 32, dA1);
            GLOAD_LDS16(gW,      dB0);
            GLOAD_LDS16(gW + 32, dB1);
        }
        __syncthreads();

#pragma unroll
        for (int h = 0; h < 2; ++h) {
            short8 af[4], bf[4];
#pragma unroll
            for (int mt = 0; mt < 4; ++mt)
                af[mt] = *(const short8*)(As0 + h * 4096 + (wm * 64 + mt * 16 + l15) * 32 + q8);
#pragma unroll
            for (int nt = 0; nt < 4; ++nt)
                bf[nt] = *(const short8*)(Bs0 + h * 4096 + (wn * 64 + nt * 16 + l15) * 32 + q8);
#pragma unroll
            for (int mt = 0; mt < 4; ++mt)
#pragma unroll
                for (int nt = 0; nt < 4; ++nt)
                    acc[mt][nt] = MFMA(af[mt], bf[nt], acc[mt][nt]);
        }
    }
    __syncthreads();                               // all LDS reads done before image reuse

    // ---- epilogue: LDS image + coalesced stores
    // (C/D frag: row = wm*64+mt*16+q4+r, col = wn*64+nt*16+l15; swz col ^= q(row)<<4)
    if (MODE != 3) {
        unsigned short* img = &sh[0];              // 128x128 bf16 = 32 KB
        float colf[4], rowf[4][4];
        if (MODE == 2) {
            const int D0 = (4 - bx) * 128;         // = (tl - jt) * 128
#pragma unroll
            for (int nt = 0; nt < 4; ++nt)
                colf[nt] = exp2f(-(float)(wn * 64 + nt * 16 + l15) * LOG2G);     // g^-col
#pragma unroll
            for (int mt = 0; mt < 4; ++mt)
#pragma unroll
                for (int r = 0; r < 4; ++r)
                    rowf[mt][r] = exp2f((float)(D0 + wm * 64 + mt * 16 + q4 + r) * LOG2G);
        }
#pragma unroll
        for (int mt = 0; mt < 4; ++mt) {
#pragma unroll
            for (int nt = 0; nt < 4; ++nt) {
#pragma unroll
                for (int r = 0; r < 4; ++r) {
                    const int row = wm * 64 + mt * 16 + q4 + r;
                    const int col = wn * 64 + nt * 16 + l15;
                    float v = acc[mt][nt][r];
                    if (MODE == 2) {
                        const int d = (4 - bx) * 128 + row - col;
                        v = (d >= 0) ? v * rowf[mt][r] * colf[nt] : 0.0f;
                    }
                    img[row * 128 + (col ^ (((row >> 2) & 3) << 4))] = f32_to_bf16_rn(v);
                }
            }
        }
        __syncthreads();
#pragma unroll
        for (int i = 0; i < 8; ++i) {
            const int c   = i * 256 + tid;         // 2048 chunks of 16B
            const int row = c >> 4;
            const int c8  = (c & 15) * 8;
            short8 v = *(const short8*)&img[row * 128 + (c8 ^ (((row >> 2) & 3) << 4))];
            if (MODE == 0) {
                const int gc = wRow0 + c8;
                if (gc < p0)
                    *(short8*)((unsigned short*)outp + (size_t)(aRow0 + row) * ldo + gc) = v;
            } else if (MODE == 1) {
                const int s  = wRow0 + c8;         // global x row (8 consecutive)
                const int hh = aRow0 + row;        // h
                *(short8*)((unsigned short*)outp +
                           ((size_t)(s >> 12) * H_DIM + hh) * S_LEN + (s & (S_LEN - 1))) = v;
            } else {                               // MODE 2
                *(short8*)((unsigned short*)outp + (size_t)tT * (128 * 640) +
                           (size_t)row * 640 + bx * 128 + c8) = v;
            }
        }
    } else {
        float* img32 = (float*)&sh[0];             // 64x128 f32 = 32 KB per pass
#pragma unroll
        for (int p = 0; p < 2; ++p) {
            if (p) __syncthreads();                // pass-0 reads done before overwrite
            if (wm == p) {
#pragma unroll
                for (int mt = 0; mt < 4; ++mt)
#pragma unroll
                    for (int nt = 0; nt < 4; ++nt)
#pragma unroll
                        for (int r = 0; r < 4; ++r) {
                            const int rl  = mt * 16 + q4 + r;          // 0..63
                            const int col = wn * 64 + nt * 16 + l15;
                            img32[rl * 128 + (col ^ (((rl >> 2) & 3) << 4))] = acc[mt][nt][r];
                        }
            }
            __syncthreads();
#pragma unroll
            for (int i = 0; i < 8; ++i) {
                const int c  = i * 256 + tid;      // 2048 chunks of 16B
                const int rl = c >> 5;             // 0..63
                const int c4 = (c & 31) * 4;
                float4 v = *(const float4*)&img32[rl * 128 + (c4 ^ (((rl >> 2) & 3) << 4))];
                *(float4*)((float*)outp + (size_t)(tT * 128 + p * 64 + rl) * H_DIM +
                           bx * 128 + c4) = v;
            }
        }
    }
}

// ---------------------------------------------------------------- launches
// L1: all prep: tr_cvt(Wq), tr_cvt(Wk), cvt Wv, x~ pad cols
__global__ __launch_bounds__(256) void prep_small(const float* __restrict__ Wq,
                                                  const float* __restrict__ bq,
                                                  const float* __restrict__ Wk,
                                                  const float* __restrict__ bk,
                                                  const float* __restrict__ Wv,
                                                  unsigned short* __restrict__ wqT,
                                                  unsigned short* __restrict__ wkT,
                                                  unsigned short* __restrict__ wvb,
                                                  unsigned short* __restrict__ xtb) {
    __shared__ float Lt[128][33];
    const int t = blockIdx.x, tid = threadIdx.x;
    if (t < 288) {
        tr_cvt_body(Lt, Wq, bq, wqT, t & 7, t >> 3, tid);
    } else if (t < 576) {
        const int t2 = t - 288;
        tr_cvt_body(Lt, Wk, bk, wkT, t2 & 7, t2 >> 3, tid);
    } else if (t < 1600) {
        cvt_bf16_body((t - 576) * 256 + tid, Wv, wvb, H_DIM * H_DIM / 4);
    } else {
        fill_pad_body((t - 1600) * 256 + tid, xtb);
    }
}

// L2: P1 (81 latency-bound blocks, first) ∪ cvt_x (8192 streaming blocks hide it)
__global__ __launch_bounds__(256) void cvtx_p1(const float* __restrict__ x,
                                               unsigned short* __restrict__ xtb,
                                               const unsigned short* __restrict__ wkT,
                                               const unsigned short* __restrict__ wqT,
                                               unsigned short* __restrict__ p1) {
    __shared__ unsigned short sh[16384];
    const int t = blockIdx.x;
    if (t < 81) {
        // P1 = W~kT . W~qT^T  (1152 x 1152 clipped to 1088 cols, K=1024)
        gemm_body<0>(sh, t % 9, t / 9, wkT, 1024, wqT, 1024, p1, HP, 1024, HP);
    } else {
        cvt_x_body((t - 81) * 256 + threadIdx.x, x, xtb);
    }
}

// L3: G = x~ . P1^T  (16384 x 1152 -> clip 1088, K=1088), XCD-swizzled, 1152 blocks
__global__ __launch_bounds__(256) void gemm_g(const unsigned short* __restrict__ xtb,
                                              const unsigned short* __restrict__ p1,
                                              unsigned short* __restrict__ gb) {
    __shared__ unsigned short sh[16384];
    const int bid = blockIdx.x;                 // 1152 = 8 * 144
    const int g = bid & 7, j = bid >> 3;
    gemm_body<0>(sh, j % 9, g * 16 + j / 9, xtb, HP, p1, HP, gb, HP, HP, HP);
}

// L4: Pb (640 blocks first) ∪ Vt (1024 blocks behind; fills CUs around Pb's early-exits)
__global__ __launch_bounds__(256) void pb_vt(const unsigned short* __restrict__ gb,
                                             const unsigned short* __restrict__ xtb,
                                             const unsigned short* __restrict__ wvb,
                                             unsigned short* __restrict__ pb,
                                             unsigned short* __restrict__ vtb) {
    __shared__ unsigned short sh[16384];
    const int t = blockIdx.x;
    if (t < 640) {
        // Pb = band(G . x~^T) * gamma^d  (5 slots of 128 per q-tile, K=1088)
        const int g = t & 7, j = t >> 3;        // 640 = 8 * 80
        gemm_body<2>(sh, j % 5, g * 16 + j / 5, gb, HP, xtb, HP, pb, 640, HP, 0);
    } else {
        // Vt = Wv . x~^T scattered to [b][h][s]  (K=1024)
        const int t2 = t - 640;
        const int g = t2 & 7, j = t2 >> 3;      // 1024 = 8 * 128
        gemm_body<1>(sh, j & 7, g * 16 + (j >> 3), wvb, 1024, xtb, HP, vtb, 0, 1024, 0);
    }
}

// L5: out = Pb . Vt^T  (banded K<=640 via kStart, f32), 1024 blocks
__global__ __launch_bounds__(256) void gemm_out(const unsigned short* __restrict__ pb,
                                                const unsigned short* __restrict__ vtb,
                                                float* __restrict__ out) {
    __shared__ unsigned short sh[16384];
    const int bid = blockIdx.x;                 // 1024 = 8 * 128
    const int g = bid & 7, j = bid >> 3;
    gemm_body<3>(sh, j & 7, g * 16 + (j >> 3), pb, 640, vtb, S_LEN, out, H_DIM, 640, 0);
}

// ---------------------------------------------------------------- launcher
extern "C" void kernel_launch(void* const* d_in, const int* in_sizes, int n_in,
                              void* d_out, int out_size, void* d_ws, size_t ws_size,
                              hipStream_t stream) {
    (void)in_sizes; (void)n_in; (void)out_size; (void)ws_size;

    const float* x  = (const float*)d_in[0];
    const float* Wq = (const float*)d_in[1];
    const float* bq = (const float*)d_in[2];
    const float* Wk = (const float*)d_in[3];
    const float* bk = (const float*)d_in[4];
    const float* Wv = (const float*)d_in[5];
    float* out = (float*)d_out;

    unsigned short* xtb = (unsigned short*)d_ws;                    // 16384*1088*2 = 35.7 MB
    unsigned short* gb  = xtb + (size_t)NROWS * HP;                 // 35.7 MB
    unsigned short* vtb = gb  + (size_t)NROWS * HP;                 // 33.6 MB
    unsigned short* pb  = vtb + (size_t)NROWS * H_DIM;              // 128*128*640*2 = 21.0 MB
    unsigned short* wqT = pb  + (size_t)128 * 128 * 640;            // 1152*1024*2 = 2.36 MB
    unsigned short* wkT = wqT + (size_t)WR * H_DIM;                 // 2.36 MB
    unsigned short* p1  = wkT + (size_t)WR * H_DIM;                 // 1152*1088*2 = 2.5 MB
    unsigned short* wvb = p1  + (size_t)WR * HP;                    // 2.1 MB
    // total ~= 135 MB

    prep_small<<<2112, 256, 0, stream>>>(Wq, bq, Wk, bk, Wv, wqT, wkT, wvb, xtb);
    cvtx_p1<<<81 + 8192, 256, 0, stream>>>(x, xtb, wkT, wqT, p1);
    gemm_g<<<1152, 256, 0, stream>>>(xtb, p1, gb);
    pb_vt<<<640 + 1024, 256, 0, stream>>>(gb, xtb, wvb, pb, vtb);
    gemm_out<<<1024, 256, 0, stream>>>(pb, vtb, out);
}

// Round 7
// 281.087 us; speedup vs baseline: 1.1101x; 1.1101x over previous
//
#include <hip/hip_runtime.h>

// Retention, B=4 S=4096 H=1024, gamma=0.96875.
// out[b,i,:] = sum_{j<=i} gamma^(i-j) * (q_i . k_j) * v_j
//
// Pipeline (all bf16 MFMA GEMMs, 128x128 tile, BK=64 double-half staging, XCD-swizzled grids):
//   x~   = [x | 1 | 0pad63]               (16384 x 1088 bf16)
//   W~qT = [Wq^T ; bq ; 0pad]             (1152 x 1024 bf16)   (same for k)
//   P1   = W~kT . W~qT^T                  (1152 x 1088)
//   G    = x~ . P1^T = x~ M~              (16384 x 1088)
//   Vt   = (Wv . x~^T) scattered          ([b][h][s] bf16)
//   Pb   = band(G . x~^T) * gamma^d       (128 qtiles x 128 x 384 bf16)
//   out  = Pb . Vt^T (banded K<=384)      (f32)
//
// R7 change: band 5 -> 3 key-slots (window 256..383).  gamma^256 = 3.0e-4;
// truncated-tail per-output std ~= 32*g^257/sqrt(1-g^2) ~= 0.04 (worst case 0.3)
// vs output std ~128 and tol 6.0 — three orders of margin.  Saves 17.7 GF
// (Pb 22.8->13.7, out 21.5->12.9), shrinks pb 21->12.6 MB, and cuts Pb-stage
// L2/L3 operand re-reads by 40% (G and x~ band read 3x not 5x) — the counters
// across R1-R6 show all schedule variants pinned at 600-720 TF with cache-level
// traffic ~10 TB/s, so work/traffic reduction is the reliable lever.
// Base structure = R1 (best measured, 304 us): 128^2 m97-style GEMM, 5 fused
// launches, Pb/P1 latency-bound grids co-scheduled behind streaming work.

typedef __attribute__((ext_vector_type(8))) short short8;   // 8 bf16 = 4 VGPRs
typedef __attribute__((ext_vector_type(4))) float floatx4;  // MFMA 16x16 C/D

#define MFMA(a, b, c) __builtin_amdgcn_mfma_f32_16x16x32_bf16((a), (b), (c), 0, 0, 0)

#define B_SZ   4
#define S_LEN  4096
#define H_DIM  1024
#define NROWS  (B_SZ * S_LEN)          // 16384
#define HP     1088                    // padded H+1 (17*64)
#define WR     1152                    // padded weight rows (9*128)
#define KB3    384                     // band width (3 slots of 128)
#define LOG2G  (-0.045803690f)         // log2(0.96875)

__device__ __forceinline__ unsigned short f32_to_bf16_rn(float f) {
    unsigned int u = __float_as_uint(f);
    u += 0x7FFFu + ((u >> 16) & 1u);   // round-to-nearest-even
    return (unsigned short)(u >> 16);
}

#define GLOAD_LDS16(gptr, lptr)                                                        \
    __builtin_amdgcn_global_load_lds((__attribute__((address_space(1))) void*)(gptr),  \
                                     (__attribute__((address_space(3))) void*)(lptr),  \
                                     16, 0, 0)

// ---------------------------------------------------------------- elementwise bodies
__device__ __forceinline__ void cvt_bf16_body(int i, const float* __restrict__ src,
                                              unsigned short* __restrict__ dst, int n4) {
    if (i >= n4) return;
    float4 v = ((const float4*)src)[i];
    ushort4 o;
    o.x = f32_to_bf16_rn(v.x);
    o.y = f32_to_bf16_rn(v.y);
    o.z = f32_to_bf16_rn(v.z);
    o.w = f32_to_bf16_rn(v.w);
    ((ushort4*)dst)[i] = o;
}

// x -> x~ rows of HP (cols 0..1023)
__device__ __forceinline__ void cvt_x_body(int idx, const float* __restrict__ src,
                                           unsigned short* __restrict__ dst) {
    int row = idx >> 7, c8 = (idx & 127) * 8;
    const float4* s = (const float4*)(src + (size_t)row * H_DIM + c8);
    float4 a = s[0], b = s[1];
    ushort4 o0, o1;
    o0.x = f32_to_bf16_rn(a.x); o0.y = f32_to_bf16_rn(a.y);
    o0.z = f32_to_bf16_rn(a.z); o0.w = f32_to_bf16_rn(a.w);
    o1.x = f32_to_bf16_rn(b.x); o1.y = f32_to_bf16_rn(b.y);
    o1.z = f32_to_bf16_rn(b.z); o1.w = f32_to_bf16_rn(b.w);
    ushort4* d = (ushort4*)(dst + (size_t)row * HP + c8);
    d[0] = o0; d[1] = o1;
}

// cols 1024..1087 of x~: 1.0 at col 1024, zeros elsewhere
__device__ __forceinline__ void fill_pad_body(int idx, unsigned short* __restrict__ dst) {
    int row = idx >> 3, c = idx & 7;
    uint4 v; v.x = (c == 0) ? 0x00003F80u : 0u; v.y = 0u; v.z = 0u; v.w = 0u;
    *(uint4*)(dst + (size_t)row * HP + 1024 + c * 8) = v;
}

// W (f32) + bias -> [W^T ; bias ; 0] bf16, 1152x1024.  (bx in [0,8), by in [0,36))
__device__ __forceinline__ void tr_cvt_body(float (&Lt)[128][33],
                                            const float* __restrict__ Wsrc,
                                            const float* __restrict__ bias,
                                            unsigned short* __restrict__ dst,
                                            int bx, int by, int tid) {
    if (by >= 32) {                                // rows 1024..1151: bias row + zeros
        if (bx != 0) return;
        const int h0 = by * 32;
#pragma unroll
        for (int i = 0; i < 128; ++i) {
            int idx = i * 256 + tid;               // 32*1024
            int r = idx >> 10, cc = idx & 1023;
            int h = h0 + r;
            float v = (h == 1024) ? bias[cc] : 0.0f;
            dst[(size_t)h * 1024 + cc] = f32_to_bf16_rn(v);
        }
        return;
    }
    const int w0 = bx * 128, h0 = by * 32;
#pragma unroll
    for (int i = 0; i < 16; ++i) {
        int idx = i * 256 + tid;
        int r = idx >> 5, cc = idx & 31;
        Lt[r][cc] = Wsrc[(size_t)(w0 + r) * 1024 + h0 + cc];
    }
    __syncthreads();
#pragma unroll
    for (int i = 0; i < 16; ++i) {
        int idx = i * 256 + tid;
        int hh = idx >> 7, ww = idx & 127;
        dst[(size_t)(h0 + hh) * 1024 + w0 + ww] = f32_to_bf16_rn(Lt[ww][hh]);
    }
}

// ---------------------------------------------------------------- generic 128x128 MFMA GEMM body
// C[n,o] = sum_k A[n,k]*W[o,k].  BK=64 as two 32-halves (32 KB LDS), 2 barriers / 64K.
// MODE 0: bf16 row-major store (col-clip p0)   MODE 1: Vt scatter (by=xtile, bx=htile)
// MODE 2: decay epilogue -> Pb band (3 slots)  MODE 3: banded-K (<=384), f32 store
template <int MODE>
__device__ __forceinline__ void gemm_body(unsigned short (&As)[2][128 * 32],
                                          unsigned short (&Bs)[2][128 * 32],
                                          int bx, int by,
                                          const unsigned short* __restrict__ A, int lda,
                                          const unsigned short* __restrict__ W, int ldw,
                                          void* __restrict__ outp, int ldo, int K, int p0) {
    const int tid  = threadIdx.x;
    const int lane = tid & 63;
    const int w4   = tid >> 6;
    const int wm   = w4 >> 1, wn = w4 & 1;
    const int l15  = lane & 15;
    const int q8   = (lane >> 4) * 8;
    const int q4   = (lane >> 4) * 4;

    int aRow0 = 0, wRow0 = 0, kStart = 0;
    const unsigned short* Ap = A;
    const unsigned short* Wp = W;
    const int tT = by;
    const int tl = tT & 31;
    int jt = 0;

    if (MODE == 0) {
        aRow0 = by * 128; wRow0 = bx * 128;
    } else if (MODE == 1) {
        aRow0 = bx * 128; wRow0 = by * 128;       // bx=h-tile, by=x-row-tile (localized)
    } else if (MODE == 2) {
        jt = tl - 2 + bx;
        if (jt < 0) return;                        // block-uniform early exit
        aRow0 = tT * 128;
        wRow0 = (tT >> 5) * S_LEN + jt * 128;
    } else {                                       // MODE 3
        kStart = (tl < 2) ? (2 - tl) * 128 : 0;
        Ap = A + (size_t)tT * 128 * KB3;
        Wp = W + (size_t)((tT >> 5) * H_DIM + bx * 128) * S_LEN + (ptrdiff_t)(tl - 2) * 128;
    }

    floatx4 acc[4][4];
#pragma unroll
    for (int i = 0; i < 4; ++i)
#pragma unroll
        for (int j = 0; j < 4; ++j) acc[i][j] = (floatx4)0.0f;

    for (int k0 = kStart; k0 < K; k0 += 64) {
        __syncthreads();
#pragma unroll
        for (int p = 0; p < 2; ++p) {
            const int c = p * 256 + tid;           // chunk id in [0,512): row=c>>2, ch=c&3
            const unsigned short* gA = Ap + (size_t)(aRow0 + (c >> 2)) * lda + k0 + (c & 3) * 8;
            const unsigned short* gW = Wp + (size_t)(wRow0 + (c >> 2)) * ldw + k0 + (c & 3) * 8;
            char* dA0 = (char*)&As[0][0] + (size_t)(p * 256 + w4 * 64) * 16;
            char* dA1 = (char*)&As[1][0] + (size_t)(p * 256 + w4 * 64) * 16;
            char* dB0 = (char*)&Bs[0][0] + (size_t)(p * 256 + w4 * 64) * 16;
            char* dB1 = (char*)&Bs[1][0] + (size_t)(p * 256 + w4 * 64) * 16;
            GLOAD_LDS16(gA,      dA0);
            GLOAD_LDS16(gA + 32, dA1);
            GLOAD_LDS16(gW,      dB0);
            GLOAD_LDS16(gW + 32, dB1);
        }
        __syncthreads();

#pragma unroll
        for (int h = 0; h < 2; ++h) {
            short8 af[4], bf[4];
#pragma unroll
            for (int mt = 0; mt < 4; ++mt)
                af[mt] = *(const short8*)(&As[h][0] + (wm * 64 + mt * 16 + l15) * 32 + q8);
#pragma unroll
            for (int nt = 0; nt < 4; ++nt)
                bf[nt] = *(const short8*)(&Bs[h][0] + (wn * 64 + nt * 16 + l15) * 32 + q8);
#pragma unroll
            for (int mt = 0; mt < 4; ++mt)
#pragma unroll
                for (int nt = 0; nt < 4; ++nt)
                    acc[mt][nt] = MFMA(af[mt], bf[nt], acc[mt][nt]);
        }
    }

    // ---- epilogue (C/D layout: col=lane&15, row=(lane>>4)*4+r)
#pragma unroll
    for (int nt = 0; nt < 4; ++nt) {
        const int ol = wn * 64 + nt * 16 + l15;
#pragma unroll
        for (int mt = 0; mt < 4; ++mt) {
#pragma unroll
            for (int r = 0; r < 4; ++r) {
                const int nl = wm * 64 + mt * 16 + q4 + r;
                const float v = acc[mt][nt][r];
                if (MODE == 0) {
                    const int o = wRow0 + ol;
                    if (o < p0)
                        ((unsigned short*)outp)[(size_t)(aRow0 + nl) * ldo + o] = f32_to_bf16_rn(v);
                } else if (MODE == 1) {
                    const int s = wRow0 + ol;              // global x row
                    const int hh = aRow0 + nl;             // h
                    ((unsigned short*)outp)[((size_t)(s >> 12) * H_DIM + hh) * S_LEN + (s & (S_LEN - 1))] =
                        f32_to_bf16_rn(v);
                } else if (MODE == 2) {
                    const int d = (tl - jt) * 128 + nl - ol;
                    const float pv = (d >= 0) ? v * exp2f((float)d * LOG2G) : 0.0f;
                    ((unsigned short*)outp)[(size_t)tT * (128 * KB3) + (size_t)nl * KB3 +
                                            (size_t)bx * 128 + ol] = f32_to_bf16_rn(pv);
                } else {                                   // MODE 3
                    ((float*)outp)[(size_t)(tT * 128 + nl) * H_DIM + bx * 128 + ol] = v;
                }
            }
        }
    }
}

// ---------------------------------------------------------------- fused launches
// L1: all prep (independent): tr_cvt(Wq), tr_cvt(Wk), cvt Wv, x~ pad cols
__global__ __launch_bounds__(256) void prep_small(const float* __restrict__ Wq,
                                                  const float* __restrict__ bq,
                                                  const float* __restrict__ Wk,
                                                  const float* __restrict__ bk,
                                                  const float* __restrict__ Wv,
                                                  unsigned short* __restrict__ wqT,
                                                  unsigned short* __restrict__ wkT,
                                                  unsigned short* __restrict__ wvb,
                                                  unsigned short* __restrict__ xtb) {
    __shared__ float Lt[128][33];
    const int t = blockIdx.x, tid = threadIdx.x;
    if (t < 288) {
        tr_cvt_body(Lt, Wq, bq, wqT, t & 7, t >> 3, tid);
    } else if (t < 576) {
        const int t2 = t - 288;
        tr_cvt_body(Lt, Wk, bk, wkT, t2 & 7, t2 >> 3, tid);
    } else if (t < 1600) {
        cvt_bf16_body((t - 576) * 256 + tid, Wv, wvb, H_DIM * H_DIM / 4);
    } else {
        fill_pad_body((t - 1600) * 256 + tid, xtb);
    }
}

// L2: P1 (81 latency-bound blocks, first) ∪ cvt_x (8192 streaming blocks hide it)
__global__ __launch_bounds__(256) void cvtx_p1(const float* __restrict__ x,
                                               unsigned short* __restrict__ xtb,
                                               const unsigned short* __restrict__ wkT,
                                               const unsigned short* __restrict__ wqT,
                                               unsigned short* __restrict__ p1) {
    __shared__ unsigned short As[2][128 * 32];
    __shared__ unsigned short Bs[2][128 * 32];
    const int t = blockIdx.x;
    if (t < 81) {
        // P1 = W~kT . W~qT^T  (1152 x 1088, K=1024)
        gemm_body<0>(As, Bs, t % 9, t / 9, wkT, 1024, wqT, 1024, p1, HP, 1024, HP);
    } else {
        cvt_x_body((t - 81) * 256 + threadIdx.x, x, xtb);
    }
}

// L3: G = x~ . P1^T  (16384 x 1088, K=1088), XCD-swizzled
__global__ __launch_bounds__(256) void gemm_g(const unsigned short* __restrict__ xtb,
                                              const unsigned short* __restrict__ p1,
                                              unsigned short* __restrict__ gb) {
    __shared__ unsigned short As[2][128 * 32];
    __shared__ unsigned short Bs[2][128 * 32];
    const int bid = blockIdx.x;
    const int g = bid & 7, j = bid >> 3;
    gemm_body<0>(As, Bs, j % 9, g * 16 + j / 9, xtb, HP, p1, HP, gb, HP, HP, HP);
}

// L4: Pb (384 blocks, latency-exposed — first) ∪ Vt (1024 throughput blocks behind).
// Both sub-ranges 8-aligned so bid&7 XCD swizzle holds.
__global__ __launch_bounds__(256) void pb_vt(const unsigned short* __restrict__ gb,
                                             const unsigned short* __restrict__ xtb,
                                             const unsigned short* __restrict__ wvb,
                                             unsigned short* __restrict__ pb,
                                             unsigned short* __restrict__ vtb) {
    __shared__ unsigned short As[2][128 * 32];
    __shared__ unsigned short Bs[2][128 * 32];
    const int t = blockIdx.x;
    if (t < 384) {
        // Pb = band(G . x~^T) * gamma^d  (3 slots per q-tile, K=1088)
        const int g = t & 7, j = t >> 3;        // 384 = 8 * 48
        gemm_body<2>(As, Bs, j % 3, g * 16 + j / 3, gb, HP, xtb, HP, pb, KB3, HP, 0);
    } else {
        // Vt = Wv . x~^T scattered to [b][h][s]  (K=1024)
        const int t2 = t - 384;
        const int g = t2 & 7, j = t2 >> 3;      // 1024 = 8 * 128
        gemm_body<1>(As, Bs, j & 7, g * 16 + (j >> 3), wvb, 1024, xtb, HP, vtb, 0, 1024, 0);
    }
}

// L5: out = Pb . Vt^T  (banded K<=384, f32)
__global__ __launch_bounds__(256) void gemm_out(const unsigned short* __restrict__ pb,
                                                const unsigned short* __restrict__ vtb,
                                                float* __restrict__ out) {
    __shared__ unsigned short As[2][128 * 32];
    __shared__ unsigned short Bs[2][128 * 32];
    const int bid = blockIdx.x;                 // 1024 = 8 * 128
    const int g = bid & 7, j = bid >> 3;
    gemm_body<3>(As, Bs, j & 7, g * 16 + (j >> 3), pb, KB3, vtb, S_LEN, out, H_DIM, KB3, 0);
}

// ---------------------------------------------------------------- launcher
extern "C" void kernel_launch(void* const* d_in, const int* in_sizes, int n_in,
                              void* d_out, int out_size, void* d_ws, size_t ws_size,
                              hipStream_t stream) {
    (void)in_sizes; (void)n_in; (void)out_size; (void)ws_size;

    const float* x  = (const float*)d_in[0];
    const float* Wq = (const float*)d_in[1];
    const float* bq = (const float*)d_in[2];
    const float* Wk = (const float*)d_in[3];
    const float* bk = (const float*)d_in[4];
    const float* Wv = (const float*)d_in[5];
    float* out = (float*)d_out;

    unsigned short* xtb = (unsigned short*)d_ws;                    // 16384*1088*2 = 35.7 MB
    unsigned short* gb  = xtb + (size_t)NROWS * HP;                 // 35.7 MB
    unsigned short* vtb = gb  + (size_t)NROWS * HP;                 // 33.6 MB
    unsigned short* pb  = vtb + (size_t)NROWS * H_DIM;              // 128*128*384*2 = 12.6 MB
    unsigned short* wqT = pb  + (size_t)128 * 128 * KB3;            // 2.36 MB
    unsigned short* wkT = wqT + (size_t)WR * H_DIM;                 // 2.36 MB
    unsigned short* p1  = wkT + (size_t)WR * H_DIM;                 // 1152*1088*2 = 2.5 MB
    unsigned short* wvb = p1  + (size_t)WR * HP;                    // 2.1 MB
    // total ~= 127 MB

    prep_small<<<2112, 256, 0, stream>>>(Wq, bq, Wk, bk, Wv, wqT, wkT, wvb, xtb);
    cvtx_p1<<<81 + 8192, 256, 0, stream>>>(x, xtb, wkT, wqT, p1);
    gemm_g<<<9 * 128, 256, 0, stream>>>(xtb, p1, gb);
    pb_vt<<<384 + 1024, 256, 0, stream>>>(gb, xtb, wvb, pb, vtb);
    gemm_out<<<8 * 128, 256, 0, stream>>>(pb, vtb, out);
}